// Round 1
// baseline (430.996 us; speedup 1.0000x reference)
//
#include <hip/hip_runtime.h>
#include <stdint.h>

typedef unsigned short u16;
typedef __bf16 bf16x8 __attribute__((ext_vector_type(8)));
typedef float f32x4 __attribute__((ext_vector_type(4)));
typedef unsigned short u16x8 __attribute__((ext_vector_type(8)));
typedef unsigned short u16x4 __attribute__((ext_vector_type(4)));

#define HD 16
#define BB 4
#define SS 2048
#define DD 1024
#define DH 64

__device__ __forceinline__ u16 f2bf(float f) {
  union { float f; uint32_t u; } v; v.f = f;
  uint32_t u = v.u;
  return (u16)((u + 0x7FFFu + ((u >> 16) & 1u)) >> 16);  // RNE, no NaN in data
}

__device__ __forceinline__ void gl2lds16(const void* g, void* l) {
  __builtin_amdgcn_global_load_lds(
      (const __attribute__((address_space(1))) void*)g,
      (__attribute__((address_space(3))) void*)l, 16, 0, 0);
}

// ---------------- cast x (fp32 -> bf16), 4 elems/thread ----------------
__global__ __launch_bounds__(256) void cast_x_kernel(const float* __restrict__ src,
                                                     u16* __restrict__ dst, int n4) {
  int i = blockIdx.x * 256 + threadIdx.x;
  if (i >= n4) return;
  float4 v = ((const float4*)src)[i];
  u16x4 o;
  o.x = f2bf(v.x); o.y = f2bf(v.y); o.z = f2bf(v.z); o.w = f2bf(v.w);
  ((u16x4*)dst)[i] = o;
}

// ------------- transpose + cast weight: src fp32 [1024][1024] -> dst bf16 [n][k] -------------
__global__ __launch_bounds__(256) void wtrans_kernel(const float* __restrict__ src,
                                                     u16* __restrict__ dst) {
  __shared__ u16 tile[64][65];
  const int bx = blockIdx.x * 64;  // src col (n)
  const int by = blockIdx.y * 64;  // src row (k)
  const int t = threadIdx.x;
  const int c = t & 63, r0 = t >> 6;
#pragma unroll
  for (int r = r0; r < 64; r += 4)
    tile[r][c] = f2bf(src[(size_t)(by + r) * 1024 + bx + c]);
  __syncthreads();
#pragma unroll
  for (int r = r0; r < 64; r += 4)
    dst[(size_t)(bx + r) * 1024 + by + c] = tile[c][r];
}

// ------------- V transpose: qkv[b*S+s][2048 + h*64 + d] -> vt[((b*16+h)*64+d)][s] -------------
__global__ __launch_bounds__(256) void vtrans_kernel(const u16* __restrict__ qkv,
                                                     u16* __restrict__ vt) {
  __shared__ u16 tile[64][65];
  const int s0 = blockIdx.x * 64;
  const int h = blockIdx.y;
  const int b = blockIdx.z;
  const int t = threadIdx.x;
  const int c = t & 63, r0 = t >> 6;
#pragma unroll
  for (int r = r0; r < 64; r += 4)
    tile[r][c] = qkv[(size_t)(b * SS + s0 + r) * 3072 + 2048 + h * DH + c];
  __syncthreads();
#pragma unroll
  for (int r = r0; r < 64; r += 4)
    vt[((size_t)(b * HD + h) * DH + r) * SS + s0 + c] = tile[c][r];
}

// ---------------- NT GEMM: C[M][N] = A[M][K] * Bt[N][K]^T (bf16 in, bf16/f32 out) ----------------
template <int OUT_BF16>
__global__ __launch_bounds__(256) void gemm_nt_kernel(const u16* __restrict__ A,
                                                      const u16* __restrict__ Bt,
                                                      void* __restrict__ Cv,
                                                      int M, int N, int K) {
  __shared__ __attribute__((aligned(16))) u16 As[128 * 32];
  __shared__ __attribute__((aligned(16))) u16 Bs[128 * 32];
  const int t = threadIdx.x;
  const int lane = t & 63;
  const int w = t >> 6;
  const int m0 = blockIdx.y * 128;
  const int n0 = blockIdx.x * 128;

  f32x4 acc[4][4] = {};

  const int srow = t >> 2;  // staging row within pass (0..63)
  const int cpos = t & 3;   // LDS chunk slot
  const int wm = (w >> 1) * 64;
  const int wn = (w & 1) * 64;
  const int kg = lane >> 4;
  const int lr = lane & 15;

  for (int k0 = 0; k0 < K; k0 += 32) {
#pragma unroll
    for (int p = 0; p < 2; ++p) {
      int row = p * 64 + srow;
      int cc = cpos ^ (row & 3);  // XOR-swizzle: kills LDS read bank conflicts
      gl2lds16(A + (size_t)(m0 + row) * K + k0 + cc * 8, (char*)As + p * 4096 + w * 1024);
      gl2lds16(Bt + (size_t)(n0 + row) * K + k0 + cc * 8, (char*)Bs + p * 4096 + w * 1024);
    }
    __syncthreads();

    bf16x8 af[4], bfr[4];
#pragma unroll
    for (int i = 0; i < 4; ++i) {
      int ra = wm + i * 16 + lr;
      af[i] = *(const bf16x8*)(As + ra * 32 + ((kg ^ (ra & 3)) * 8));
      int rb = wn + i * 16 + lr;
      bfr[i] = *(const bf16x8*)(Bs + rb * 32 + ((kg ^ (rb & 3)) * 8));
    }
#pragma unroll
    for (int i = 0; i < 4; ++i)
#pragma unroll
      for (int j = 0; j < 4; ++j)
        acc[i][j] = __builtin_amdgcn_mfma_f32_16x16x32_bf16(af[i], bfr[j], acc[i][j], 0, 0, 0);
    __syncthreads();
  }

#pragma unroll
  for (int i = 0; i < 4; ++i)
#pragma unroll
    for (int j = 0; j < 4; ++j)
#pragma unroll
      for (int r = 0; r < 4; ++r) {
        int gr = m0 + wm + i * 16 + kg * 4 + r;
        int gc = n0 + wn + j * 16 + lr;
        float v = acc[i][j][r];
        if (OUT_BF16)
          ((u16*)Cv)[(size_t)gr * N + gc] = f2bf(v);
        else
          ((float*)Cv)[(size_t)gr * N + gc] = v;
      }
}

// ---------------- flash attention: per (qtile64, h, b) ----------------
__global__ __launch_bounds__(256) void attn_kernel(const u16* __restrict__ qkv,
                                                   const u16* __restrict__ vt,
                                                   u16* __restrict__ ctx) {
  __shared__ __attribute__((aligned(16))) u16 Qs[64 * 64];
  __shared__ __attribute__((aligned(16))) u16 Ks[64 * 64];
  __shared__ __attribute__((aligned(16))) u16 Vs[64 * 64];
  __shared__ __attribute__((aligned(16))) u16 Ps[64 * 72];

  const int t = threadIdx.x;
  const int lane = t & 63;
  const int w = t >> 6;
  const int q0 = blockIdx.x * 64;
  const int h = blockIdx.y;
  const int b = blockIdx.z;

  const int srow = t >> 3;  // staging row (0..31 per pass)
  const int cpos = t & 7;
  const size_t qkv_row0 = (size_t)(b * SS) * 3072;
  const size_t vtbase = ((size_t)(b * HD + h) * DH) * SS;

  // stage Q tile once ([64 q][64 d], swizzled)
#pragma unroll
  for (int p = 0; p < 2; ++p) {
    int r = p * 32 + srow;
    int cc = cpos ^ (r & 7);
    gl2lds16(qkv + qkv_row0 + (size_t)(q0 + r) * 3072 + h * DH + cc * 8,
             (char*)Qs + p * 4096 + w * 1024);
  }

  const int lr = lane & 15, kg = lane >> 4;
  f32x4 o[4] = {};
  float m_i[4], l_i[4];
#pragma unroll
  for (int r = 0; r < 4; ++r) { m_i[r] = -1e30f; l_i[r] = 0.f; }

  for (int k0 = 0; k0 < SS; k0 += 64) {
    // stage K tile ([64 key][64 d]) and V^T tile ([64 d][64 key])
#pragma unroll
    for (int p = 0; p < 2; ++p) {
      int r = p * 32 + srow;
      int cc = cpos ^ (r & 7);
      gl2lds16(qkv + qkv_row0 + (size_t)(k0 + r) * 3072 + 1024 + h * DH + cc * 8,
               (char*)Ks + p * 4096 + w * 1024);
      gl2lds16(vt + vtbase + (size_t)r * SS + k0 + cc * 8,
               (char*)Vs + p * 4096 + w * 1024);
    }
    __syncthreads();

    // S = Q K^T for this wave's 16 q-rows x 64 keys
    f32x4 c4[4] = {};
#pragma unroll
    for (int ks = 0; ks < 2; ++ks) {
      int ra = w * 16 + lr;
      bf16x8 a = *(const bf16x8*)(Qs + ra * 64 + (((ks * 4 + kg) ^ (ra & 7)) * 8));
#pragma unroll
      for (int nt = 0; nt < 4; ++nt) {
        int rb = nt * 16 + lr;
        bf16x8 bk = *(const bf16x8*)(Ks + rb * 64 + (((ks * 4 + kg) ^ (rb & 7)) * 8));
        c4[nt] = __builtin_amdgcn_mfma_f32_16x16x32_bf16(a, bk, c4[nt], 0, 0, 0);
      }
    }
#pragma unroll
    for (int nt = 0; nt < 4; ++nt) c4[nt] = c4[nt] * 0.03125f;  // 1/sqrt(D)

    // online softmax (rows kg*4+r, replicated over 16-lane groups)
    float alpha[4];
#pragma unroll
    for (int r = 0; r < 4; ++r) {
      float mx = fmaxf(fmaxf(c4[0][r], c4[1][r]), fmaxf(c4[2][r], c4[3][r]));
#pragma unroll
      for (int off = 1; off < 16; off <<= 1) mx = fmaxf(mx, __shfl_xor(mx, off, 64));
      float mnew = fmaxf(m_i[r], mx);
      alpha[r] = __expf(m_i[r] - mnew);
      m_i[r] = mnew;
      float rs = 0.f;
#pragma unroll
      for (int nt = 0; nt < 4; ++nt) {
        float p = __expf(c4[nt][r] - mnew);
        c4[nt][r] = p;
        rs += p;
      }
#pragma unroll
      for (int off = 1; off < 16; off <<= 1) rs += __shfl_xor(rs, off, 64);
      l_i[r] = l_i[r] * alpha[r] + rs;
    }

    // P (C-layout) -> LDS (A-layout source), bf16
#pragma unroll
    for (int nt = 0; nt < 4; ++nt)
#pragma unroll
      for (int r = 0; r < 4; ++r)
        Ps[(w * 16 + kg * 4 + r) * 72 + nt * 16 + lr] = f2bf(c4[nt][r]);

    // rescale O
#pragma unroll
    for (int nt = 0; nt < 4; ++nt)
#pragma unroll
      for (int r = 0; r < 4; ++r) o[nt][r] *= alpha[r];

    // O += P V   (B-operand from V^T rows = d)
#pragma unroll
    for (int ks = 0; ks < 2; ++ks) {
      int ra = w * 16 + lr;
      bf16x8 a = *(const bf16x8*)(Ps + ra * 72 + ks * 32 + kg * 8);
#pragma unroll
      for (int nt = 0; nt < 4; ++nt) {
        int rb = nt * 16 + lr;
        bf16x8 bv = *(const bf16x8*)(Vs + rb * 64 + (((ks * 4 + kg) ^ (rb & 7)) * 8));
        o[nt] = __builtin_amdgcn_mfma_f32_16x16x32_bf16(a, bv, o[nt], 0, 0, 0);
      }
    }
    __syncthreads();  // protect Ks/Vs before next staging
  }

  // epilogue: normalize, stage through LDS, coalesced bf16 store to ctx[b,s,h*64+d]
#pragma unroll
  for (int nt = 0; nt < 4; ++nt)
#pragma unroll
    for (int r = 0; r < 4; ++r)
      Ps[(w * 16 + kg * 4 + r) * 72 + nt * 16 + lr] = f2bf(o[nt][r] / l_i[r]);

  const int rr = lane >> 3;  // 0..7
  const int cc8 = lane & 7;  // 16B chunk
#pragma unroll
  for (int p = 0; p < 2; ++p) {
    int row = p * 8 + rr;
    u16x8 vv = *(const u16x8*)(Ps + (w * 16 + row) * 72 + cc8 * 8);
    *(u16x8*)(ctx + (size_t)(b * SS + q0 + w * 16 + row) * DD + h * DH + cc8 * 8) = vv;
  }
}

extern "C" void kernel_launch(void* const* d_in, const int* in_sizes, int n_in,
                              void* d_out, int out_size, void* d_ws, size_t ws_size,
                              hipStream_t stream) {
  (void)in_sizes; (void)n_in; (void)out_size; (void)ws_size;
  const float* x = (const float*)d_in[0];
  const float* WQ = (const float*)d_in[1];
  const float* WK = (const float*)d_in[2];
  const float* WV = (const float*)d_in[3];
  const float* WO = (const float*)d_in[4];

  char* ws = (char*)d_ws;
  u16* xb = (u16*)ws;            ws += (size_t)8192 * 1024 * 2;   // 16.8 MB (reused as ctx)
  u16* wcat = (u16*)ws;          ws += (size_t)3072 * 1024 * 2;   // 6.3 MB
  u16* wot = (u16*)ws;           ws += (size_t)1024 * 1024 * 2;   // 2.1 MB
  u16* qkv = (u16*)ws;           ws += (size_t)8192 * 3072 * 2;   // 50.3 MB
  u16* vt = (u16*)ws;            ws += (size_t)BB * HD * DH * SS * 2;  // 16.8 MB
  u16* ctx = xb;  // x consumed by QKV GEMM before attention writes ctx

  cast_x_kernel<<<dim3(8192), dim3(256), 0, stream>>>(x, xb, 2097152);
  wtrans_kernel<<<dim3(16, 16), dim3(256), 0, stream>>>(WQ, wcat);
  wtrans_kernel<<<dim3(16, 16), dim3(256), 0, stream>>>(WK, wcat + 1024 * 1024);
  wtrans_kernel<<<dim3(16, 16), dim3(256), 0, stream>>>(WV, wcat + 2 * 1024 * 1024);
  wtrans_kernel<<<dim3(16, 16), dim3(256), 0, stream>>>(WO, wot);

  gemm_nt_kernel<1><<<dim3(24, 64), dim3(256), 0, stream>>>(xb, wcat, (void*)qkv, 8192, 3072, 1024);
  vtrans_kernel<<<dim3(32, 16, 4), dim3(256), 0, stream>>>(qkv, vt);
  attn_kernel<<<dim3(32, 16, 4), dim3(256), 0, stream>>>(qkv, vt, ctx);
  gemm_nt_kernel<0><<<dim3(8, 64), dim3(256), 0, stream>>>(ctx, wot, d_out, 8192, 1024, 1024);
}